// Round 5
// baseline (325.058 us; speedup 1.0000x reference)
//
#include <hip/hip_runtime.h>

// Problem: B=1024, F=64, D_IN=D_OUT=256, H=8, dh=32. f32 in/out, bf16 MFMA compute.
typedef __attribute__((ext_vector_type(8))) short bf16x8;
typedef __attribute__((ext_vector_type(8))) unsigned short u16x8;
typedef __attribute__((ext_vector_type(4))) unsigned short u16x4;
typedef __attribute__((ext_vector_type(4))) float f32x4;
typedef unsigned short u16;

__device__ __forceinline__ float b2f(u16 u) {
    return __builtin_bit_cast(float, (unsigned)u << 16);
}
__device__ __forceinline__ u16 f2b(float f) {  // RNE f32->bf16
    unsigned i = __builtin_bit_cast(unsigned, f);
    return (u16)((i + 0x7FFFu + ((i >> 16) & 1u)) >> 16);
}
__device__ __forceinline__ unsigned pkb(float a, float b) {  // 2xf32 -> packed bf16 pair
    return (unsigned)f2b(a) | ((unsigned)f2b(b) << 16);
}

// ---- kernel 0: f32 weights [d][w] -> bf16 WT [w][d]; z==192 converts W_lin (no transpose)
__global__ __launch_bounds__(256) void wtrans_kernel(
    const float* __restrict__ Q, const float* __restrict__ K, const float* __restrict__ V,
    const float* __restrict__ Wl, u16* __restrict__ WT, u16* __restrict__ WlB)
{
    int z = blockIdx.z;
    int tid = threadIdx.x;
    if (z == 192) {  // W_lin [w][d] is already B-operand layout; dtype-convert only
        int w0 = blockIdx.x * 64, d0 = blockIdx.y * 64;
#pragma unroll
        for (int i = 0; i < 2; ++i) {
            int idx = tid * 2 + i; int r = idx >> 3; int c8 = (idx & 7) * 8;
            const float* p = Wl + (size_t)(w0 + r) * 256 + d0 + c8;
            f32x4 a = *(const f32x4*)p, b = *(const f32x4*)(p + 4);
            u16x8 v;
            ((unsigned*)&v)[0] = pkb(a[0], a[1]); ((unsigned*)&v)[1] = pkb(a[2], a[3]);
            ((unsigned*)&v)[2] = pkb(b[0], b[1]); ((unsigned*)&v)[3] = pkb(b[2], b[3]);
            *(u16x8*)(WlB + (size_t)(w0 + r) * 256 + d0 + c8) = v;
        }
        return;
    }
    if (z > 192) return;
    int m = z >> 6, f = z & 63;
    const float* src = (m == 0 ? Q : (m == 1 ? K : V)) + (size_t)f * 65536;
    u16* dst = WT + (size_t)z * 65536;
    int w0 = blockIdx.x * 64, d0 = blockIdx.y * 64;
    __shared__ u16 tile[64][68];
#pragma unroll
    for (int i = 0; i < 2; ++i) {
        int idx = tid * 2 + i; int r = idx >> 3; int c8 = (idx & 7) * 8;
        const float* p = src + (size_t)(d0 + r) * 256 + w0 + c8;
        f32x4 a = *(const f32x4*)p, b = *(const f32x4*)(p + 4);
        u16x4 lo, hi;
        ((unsigned*)&lo)[0] = pkb(a[0], a[1]); ((unsigned*)&lo)[1] = pkb(a[2], a[3]);
        ((unsigned*)&hi)[0] = pkb(b[0], b[1]); ((unsigned*)&hi)[1] = pkb(b[2], b[3]);
        *(u16x4*)&tile[r][c8] = lo;
        *(u16x4*)&tile[r][c8 + 4] = hi;
    }
    __syncthreads();
#pragma unroll
    for (int i = 0; i < 2; ++i) {
        int idx = tid * 2 + i; int rw = idx >> 3; int c8 = (idx & 7) * 8;
        u16x8 v;
#pragma unroll
        for (int j = 0; j < 8; ++j) v[j] = tile[c8 + j][rw];
        *(u16x8*)(dst + (size_t)(w0 + rw) * 256 + d0 + c8) = v;
    }
}

// ---- kernel 1: q,k,v for one f, m fused. A staged once via swizzled LDS -> registers;
// B read straight from global (L2/L3-resident WT) -> NO barriers in the K-loop.
__global__ __launch_bounds__(256, 2) void qkv_gemm_kernel(
    const float* __restrict__ theta, const u16* __restrict__ WT, u16* __restrict__ ws, int B)
{
    int f = blockIdx.z;
    int bm0 = blockIdx.x * 128, bn0 = blockIdx.y * 128;
    __shared__ u16 smem[128 * 256];  // 64KB A-tile, chunk-swizzled
    int tid = threadIdx.x, wave = tid >> 6, lane = tid & 63;
    int l15 = lane & 15, quad = lane >> 4;
    int wm0 = (wave >> 1) * 64, wn0 = (wave & 1) * 64;

    const float* Af = theta + (size_t)f * 256;
#pragma unroll
    for (int p = 0; p < 16; ++p) {
        int id = p * 256 + tid;
        int r = id >> 5, c = id & 31;
        const float* g = Af + (size_t)(bm0 + r) * 16384 + c * 8;
        f32x4 a = *(const f32x4*)g, b = *(const f32x4*)(g + 4);
        u16x8 v;
        ((unsigned*)&v)[0] = pkb(a[0], a[1]); ((unsigned*)&v)[1] = pkb(a[2], a[3]);
        ((unsigned*)&v)[2] = pkb(b[0], b[1]); ((unsigned*)&v)[3] = pkb(b[2], b[3]);
        *(u16x8*)&smem[r * 256 + ((c ^ (r & 7)) * 8)] = v;
    }
    __syncthreads();
    bf16x8 af[4][8];
#pragma unroll
    for (int mi = 0; mi < 4; ++mi)
#pragma unroll
        for (int kk = 0; kk < 8; ++kk) {
            int row = wm0 + mi * 16 + l15;
            int pos = (kk * 4 + quad) ^ (l15 & 7);
            af[mi][kk] = *(const bf16x8*)&smem[row * 256 + pos * 8];
        }

    f32x4 acc[4][4];
    for (int m = 0; m < 3; ++m) {
        const u16* Bt = WT + (size_t)(m * 64 + f) * 65536 + (size_t)(bn0 + wn0) * 256;
#pragma unroll
        for (int mi = 0; mi < 4; ++mi)
#pragma unroll
            for (int ni = 0; ni < 4; ++ni) acc[mi][ni] = f32x4{0.f, 0.f, 0.f, 0.f};
#pragma unroll
        for (int kk = 0; kk < 8; ++kk) {
            bf16x8 bfr[4];
#pragma unroll
            for (int ni = 0; ni < 4; ++ni)
                bfr[ni] = *(const bf16x8*)(Bt + (size_t)(ni * 16 + l15) * 256 + kk * 32 + quad * 8);
#pragma unroll
            for (int mi = 0; mi < 4; ++mi)
#pragma unroll
                for (int ni = 0; ni < 4; ++ni)
                    acc[mi][ni] = __builtin_amdgcn_mfma_f32_16x16x32_bf16(af[mi][kk], bfr[ni], acc[mi][ni], 0, 0, 0);
        }
        u16* C = ws + (size_t)m * B * 16384 + (size_t)f * 256;
#pragma unroll
        for (int mi = 0; mi < 4; ++mi)
#pragma unroll
            for (int ni = 0; ni < 4; ++ni)
#pragma unroll
                for (int r = 0; r < 4; ++r)
                    C[(size_t)(bm0 + wm0 + mi * 16 + quad * 4 + r) * 16384 + bn0 + wn0 + ni * 16 + l15] =
                        f2b(acc[mi][ni][r]);
    }
}

// ---- kernel 2: attention. 1 block per b, 1 wave per head (x2 sequential heads).
__global__ __launch_bounds__(256) void attn_kernel(
    const u16* __restrict__ qws, const u16* __restrict__ kws, const u16* __restrict__ vws,
    float* __restrict__ attf, const float* __restrict__ rotw)
{
    constexpr float INV2PI = 0.15915494309189535f;
    constexpr float LOG2E = 1.4426950408889634f;
    int b = blockIdx.x;
    int tid = threadIdx.x, wave = tid >> 6, lane = tid & 63;
    int l15 = lane & 15, quad = lane >> 4;
    __shared__ u16 Sb[4][64][72];
    __shared__ u16 Vb[4][64][32];
    const size_t base = (size_t)b * (64 * 256);
    float rw[8];
    {
        f32x4 r0 = *(const f32x4*)(rotw + quad * 8);
        f32x4 r1 = *(const f32x4*)(rotw + quad * 8 + 4);
#pragma unroll
        for (int j = 0; j < 4; ++j) { rw[j] = r0[j]; rw[j + 4] = r1[j]; }
    }
    for (int hi = 0; hi < 2; ++hi) {
        int h = wave + hi * 4;
        const u16* qh = qws + base + h * 32;
        const u16* kh = kws + base + h * 32;
        const u16* vh = vws + base + h * 32;
#pragma unroll
        for (int i = 0; i < 4; ++i) {
            int row = i * 16 + (lane >> 2); int c8 = (lane & 3) * 8;
            *(u16x8*)&Vb[wave][row][c8] = *(const u16x8*)(vh + (size_t)row * 256 + c8);
        }
        bf16x8 af[4][2], bfr[4][2];
#pragma unroll
        for (int mi = 0; mi < 4; ++mi) {
            u16x8 q8 = *(const u16x8*)(qh + (size_t)(mi * 16 + l15) * 256 + quad * 8);
            float cq[8], sq[8];
#pragma unroll
            for (int j = 0; j < 8; ++j) {
                float v = b2f(q8[j]) * INV2PI;
                cq[j] = __builtin_amdgcn_cosf(v);
                sq[j] = __builtin_amdgcn_sinf(v);
            }
            u16x8 cv, sv;
#pragma unroll
            for (int j2 = 0; j2 < 4; ++j2) {
                ((unsigned*)&cv)[j2] = pkb(cq[2 * j2] * rw[2 * j2], cq[2 * j2 + 1] * rw[2 * j2 + 1]);
                ((unsigned*)&sv)[j2] = pkb(sq[2 * j2] * rw[2 * j2], sq[2 * j2 + 1] * rw[2 * j2 + 1]);
            }
            af[mi][0] = __builtin_bit_cast(bf16x8, cv);
            af[mi][1] = __builtin_bit_cast(bf16x8, sv);
        }
#pragma unroll
        for (int ni = 0; ni < 4; ++ni) {
            u16x8 k8 = *(const u16x8*)(kh + (size_t)(ni * 16 + l15) * 256 + quad * 8);
            float ck[8], sk[8];
#pragma unroll
            for (int j = 0; j < 8; ++j) {
                float v = b2f(k8[j]) * INV2PI;
                ck[j] = __builtin_amdgcn_cosf(v);
                sk[j] = __builtin_amdgcn_sinf(v);
            }
            u16x8 cv, sv;
#pragma unroll
            for (int j2 = 0; j2 < 4; ++j2) {
                ((unsigned*)&cv)[j2] = pkb(ck[2 * j2], ck[2 * j2 + 1]);
                ((unsigned*)&sv)[j2] = pkb(sk[2 * j2], sk[2 * j2 + 1]);
            }
            bfr[ni][0] = __builtin_bit_cast(bf16x8, cv);
            bfr[ni][1] = __builtin_bit_cast(bf16x8, sv);
        }
        f32x4 acc[4][4];
#pragma unroll
        for (int mi = 0; mi < 4; ++mi)
#pragma unroll
            for (int ni = 0; ni < 4; ++ni) acc[mi][ni] = f32x4{0.f, 0.f, 0.f, 0.f};
#pragma unroll
        for (int kc = 0; kc < 2; ++kc)
#pragma unroll
            for (int mi = 0; mi < 4; ++mi)
#pragma unroll
                for (int ni = 0; ni < 4; ++ni)
                    acc[mi][ni] = __builtin_amdgcn_mfma_f32_16x16x32_bf16(af[mi][kc], bfr[ni][kc], acc[mi][ni], 0, 0, 0);
#pragma unroll
        for (int mi = 0; mi < 4; ++mi)
#pragma unroll
            for (int ni = 0; ni < 4; ++ni)
#pragma unroll
                for (int r = 0; r < 4; ++r) {
                    float x = acc[mi][ni][r];
                    float sg = __builtin_amdgcn_rcpf(1.f + __builtin_amdgcn_exp2f(-LOG2E * x));
                    Sb[wave][mi * 16 + quad * 4 + r][ni * 16 + l15] = f2b(sg);
                }
        f32x4 ao[4][2];
#pragma unroll
        for (int mi = 0; mi < 4; ++mi)
#pragma unroll
            for (int n2 = 0; n2 < 2; ++n2) ao[mi][n2] = f32x4{0.f, 0.f, 0.f, 0.f};
#pragma unroll
        for (int kc = 0; kc < 2; ++kc) {
            bf16x8 pb[2];
#pragma unroll
            for (int n2 = 0; n2 < 2; ++n2)
#pragma unroll
                for (int j = 0; j < 8; ++j)
                    pb[n2][j] = (short)Vb[wave][kc * 32 + quad * 8 + j][n2 * 16 + l15];
#pragma unroll
            for (int mi = 0; mi < 4; ++mi) {
                bf16x8 pa = *(const bf16x8*)&Sb[wave][mi * 16 + l15][kc * 32 + quad * 8];
#pragma unroll
                for (int n2 = 0; n2 < 2; ++n2)
                    ao[mi][n2] = __builtin_amdgcn_mfma_f32_16x16x32_bf16(pa, pb[n2], ao[mi][n2], 0, 0, 0);
            }
        }
#pragma unroll
        for (int mi = 0; mi < 4; ++mi)
#pragma unroll
            for (int n2 = 0; n2 < 2; ++n2)
#pragma unroll
                for (int r = 0; r < 4; ++r)
                    attf[base + (size_t)(mi * 16 + quad * 4 + r) * 256 + h * 32 + n2 * 16 + l15] =
                        ao[mi][n2][r];
    }
}

// ---- kernel 3: res = att(f32, in d_out) + theta @ WlB^T, LayerNorm, f32 out (same buf).
// A staged once in swizzled LDS; B (bf16 WlB) from global registers -> no K-loop barriers.
__global__ __launch_bounds__(512, 4) void lin_ln_kernel(
    const float* __restrict__ theta, const u16* __restrict__ WlB, const float* att,
    const float* __restrict__ gamma, const float* __restrict__ beta, float* out)
{
    int tid = threadIdx.x, wave = tid >> 6, lane = tid & 63;
    int l15 = lane & 15, quad = lane >> 4;
    int bm0 = blockIdx.x * 128;
    int wm0 = (wave >> 2) * 64, wn0 = (wave & 3) * 64;
    int wn = wave & 3;
    __shared__ u16 smem[128 * 256];  // 64KB swizzled theta tile
    __shared__ float red1[128][4];
    __shared__ float red2[128][4];
#pragma unroll
    for (int p = 0; p < 8; ++p) {
        int id = p * 512 + tid;
        int r = id >> 5, c = id & 31;
        const float* g = theta + (size_t)(bm0 + r) * 256 + c * 8;
        f32x4 a = *(const f32x4*)g, b = *(const f32x4*)(g + 4);
        u16x8 v;
        ((unsigned*)&v)[0] = pkb(a[0], a[1]); ((unsigned*)&v)[1] = pkb(a[2], a[3]);
        ((unsigned*)&v)[2] = pkb(b[0], b[1]); ((unsigned*)&v)[3] = pkb(b[2], b[3]);
        *(u16x8*)&smem[r * 256 + ((c ^ (r & 7)) * 8)] = v;
    }
    __syncthreads();
    f32x4 acc[4][4];
#pragma unroll
    for (int mi = 0; mi < 4; ++mi)
#pragma unroll
        for (int ni = 0; ni < 4; ++ni) acc[mi][ni] = f32x4{0.f, 0.f, 0.f, 0.f};
#pragma unroll
    for (int kk = 0; kk < 8; ++kk) {
        bf16x8 af[4], bfr[4];
#pragma unroll
        for (int mi = 0; mi < 4; ++mi) {
            int row = wm0 + mi * 16 + l15;
            int pos = (kk * 4 + quad) ^ (l15 & 7);
            af[mi] = *(const bf16x8*)&smem[row * 256 + pos * 8];
        }
#pragma unroll
        for (int ni = 0; ni < 4; ++ni)
            bfr[ni] = *(const bf16x8*)(WlB + (size_t)(wn0 + ni * 16 + l15) * 256 + kk * 32 + quad * 8);
#pragma unroll
        for (int mi = 0; mi < 4; ++mi)
#pragma unroll
            for (int ni = 0; ni < 4; ++ni)
                acc[mi][ni] = __builtin_amdgcn_mfma_f32_16x16x32_bf16(af[mi], bfr[ni], acc[mi][ni], 0, 0, 0);
    }
    float gam[4], bet[4];
#pragma unroll
    for (int ni = 0; ni < 4; ++ni) {
        gam[ni] = gamma[wn0 + ni * 16 + l15];
        bet[ni] = beta[wn0 + ni * 16 + l15];
    }
#pragma unroll
    for (int mi = 0; mi < 4; ++mi)
#pragma unroll
        for (int ni = 0; ni < 4; ++ni)
#pragma unroll
            for (int r = 0; r < 4; ++r)
                acc[mi][ni][r] += att[(size_t)(bm0 + wm0 + mi * 16 + quad * 4 + r) * 256 + wn0 + ni * 16 + l15];
#pragma unroll
    for (int mi = 0; mi < 4; ++mi)
#pragma unroll
        for (int r = 0; r < 4; ++r) {
            float s1 = 0.f, s2 = 0.f;
#pragma unroll
            for (int ni = 0; ni < 4; ++ni) { float x = acc[mi][ni][r]; s1 += x; s2 += x * x; }
#pragma unroll
            for (int off = 1; off < 16; off <<= 1) {
                s1 += __shfl_xor(s1, off);
                s2 += __shfl_xor(s2, off);
            }
            if (l15 == 0) {
                int lr = wm0 + mi * 16 + quad * 4 + r;
                red1[lr][wn] = s1; red2[lr][wn] = s2;
            }
        }
    __syncthreads();
#pragma unroll
    for (int mi = 0; mi < 4; ++mi)
#pragma unroll
        for (int r = 0; r < 4; ++r) {
            int lr = wm0 + mi * 16 + quad * 4 + r;
            float s1 = red1[lr][0] + red1[lr][1] + red1[lr][2] + red1[lr][3];
            float s2 = red2[lr][0] + red2[lr][1] + red2[lr][2] + red2[lr][3];
            float mu = s1 * (1.f / 256.f);
            float var = s2 * (1.f / 256.f) - mu * mu;
            float inv = rsqrtf(var + 1e-5f);
#pragma unroll
            for (int ni = 0; ni < 4; ++ni) {
                float y = (acc[mi][ni][r] - mu) * inv * gam[ni] + bet[ni];
                out[(size_t)(bm0 + lr) * 256 + wn0 + ni * 16 + l15] = y;
            }
        }
}

extern "C" void kernel_launch(void* const* d_in, const int* in_sizes, int n_in,
                              void* d_out, int out_size, void* d_ws, size_t ws_size,
                              hipStream_t stream)
{
    const float* theta = (const float*)d_in[0];
    const float* Q  = (const float*)d_in[1];
    const float* K  = (const float*)d_in[2];
    const float* V  = (const float*)d_in[3];
    const float* Wl = (const float*)d_in[4];
    const float* rotw = (const float*)d_in[5];
    const float* gam = (const float*)d_in[6];
    const float* bet = (const float*)d_in[7];
    int B = in_sizes[0] / (64 * 256);  // 1024
    u16* ws = (u16*)d_ws;
    size_t per = (size_t)B * 16384;
    u16* wsq = ws;
    u16* wsk = ws + per;
    u16* wsv = ws + 2 * per;
    u16* wT  = ws + 3 * per;            // 192 transposed bf16 256x256 mats (24.6MB)
    u16* wlb = wT + (size_t)192 * 65536; // bf16 W_lin (128KB); total ws ~121MB
    float* outf = (float*)d_out;

    wtrans_kernel<<<dim3(4, 4, 193), 256, 0, stream>>>(Q, K, V, Wl, wT, wlb);
    qkv_gemm_kernel<<<dim3(B / 128, 2, 64), 256, 0, stream>>>(theta, wT, ws, B);
    attn_kernel<<<dim3(B), 256, 0, stream>>>(wsq, wsk, wsv, outf, rotw);
    lin_ln_kernel<<<dim3(B * 64 / 128), 512, 0, stream>>>(theta, wlb, outf, gam, bet, outf);
}